// Round 4
// baseline (161.273 us; speedup 1.0000x reference)
//
#include <hip/hip_runtime.h>
#include <hip/hip_bf16.h>

// Problem constants (from reference)
#define Cc   9
#define Hh   180
#define Ww   240
#define Bb   8
#define Nn   100000
#define WH   (Ww * Hh)        // 43200
#define WHC  (WH * Cc)        // 388800

// value_layer lookup table: piecewise-linear in ts over [-1,1]. 2048 intervals.
#define TSIZE 2048

// Bucketing: bucket = (batch, polarity, 2-row y-tile). mean 556 ev/bucket.
#define TPB   90               // y-tiles per batch
#define LBKT  (2 * TPB)        // 180 local buckets per batch
#define NBKT  (LBKT * Bb)      // 1440
#define CAP   1024             // >> max bucket fill (~670); overflow guarded

#define CHUNK 2048
#define CHUNKS_PB 49                       // ceil(100000/2048)
#define APPEND_BLOCKS (CHUNKS_PB * Bb)     // 392
#define TABLE_BLOCKS  257                  // 8 table points per block
#define PREP_BLOCKS   (APPEND_BLOCKS + TABLE_BLOCKS)  // 649
#define STG   64                           // staging entries per bucket

// Workspace layout (bytes)
#define SORT_OFF 0                              // uint[NBKT*CAP] = 5,898,240
#define TAB_OFF  (NBKT * CAP * 4)               // float[2049]    = 8,196
#define CURS_OFF (TAB_OFF + (TSIZE + 1) * 4)    // int[1440]      = 5,760
#define WS_NEED  (CURS_OFF + NBKT * 4)          // 5,912,196

__device__ __forceinline__ float leaky(float v) {
    return v >= 0.0f ? v : 0.1f * v;
}

// ---------- fused prep kernel ----------
// Blocks [0, APPEND_BLOCKS): pack events (4B) + bucket-append with LDS-staged
// coalesced flushes. Blocks [APPEND_BLOCKS, PREP_BLOCKS): tabulate value_layer.
__global__ __launch_bounds__(256) void prep_kernel(
        const int* __restrict__ ex, const int* __restrict__ ey,
        const int* __restrict__ ep, const float* __restrict__ t,
        const float* __restrict__ w1, const float* __restrict__ b1,
        const float* __restrict__ w2, const float* __restrict__ b2,
        const float* __restrict__ w3, const float* __restrict__ b3,
        int* __restrict__ curs, unsigned* __restrict__ sorted,
        float* __restrict__ tab) {
    __shared__ unsigned buf[LBKT * STG];   // 46,080 B staging
    __shared__ int cnt[LBKT];
    __shared__ int bse[LBKT];

    if (blockIdx.x < APPEND_BLOCKS) {
        // ---- append role ----
        const int b = blockIdx.x / CHUNKS_PB;
        const int chunk = blockIdx.x % CHUNKS_PB;
        for (int i = threadIdx.x; i < LBKT; i += 256) cnt[i] = 0;
        __syncthreads();

        int* curs_b = curs + b * LBKT;
        unsigned* sorted_b = sorted + (size_t)b * LBKT * CAP;

        const int base_e = chunk * CHUNK + threadIdx.x;
        #pragma unroll
        for (int k = 0; k < 8; ++k) {
            int e = base_e + k * 256;
            if (e < Nn) {
                int gi = b * Nn + e;
                int x = __builtin_nontemporal_load(ex + gi);
                int y = __builtin_nontemporal_load(ey + gi);
                int p = __builtin_nontemporal_load(ep + gi);
                float tf = __builtin_nontemporal_load(t + gi);
                int m = (int)(tf * 32768.0f + 0.5f);
                if (m > 32767) m = 32767;
                unsigned wv = (unsigned)x | ((unsigned)y << 8) |
                              ((unsigned)p << 16) | ((unsigned)m << 17);
                int lb = p * TPB + (y >> 1);
                int pos = atomicAdd(&cnt[lb], 1);
                if (pos < STG) {
                    buf[lb * STG + pos] = wv;
                } else {
                    // staging overflow (P ~ 1e-30 per bucket): direct append
                    int gp = atomicAdd(&curs_b[lb], 1);
                    if (gp < CAP) sorted_b[lb * CAP + gp] = wv;
                }
            }
        }
        __syncthreads();
        // one reservation atomic per bucket for the buffered entries
        if (threadIdx.x < LBKT) {
            int c = cnt[threadIdx.x];
            if (c > STG) c = STG;
            cnt[threadIdx.x] = c;
            bse[threadIdx.x] = c ? atomicAdd(&curs_b[threadIdx.x], c) : 0;
        }
        __syncthreads();
        // coalesced flush: wave w handles buckets w, w+4, ...
        const int wid = threadIdx.x >> 6;
        const int lane = threadIdx.x & 63;
        for (int lb = wid; lb < LBKT; lb += 4) {
            int c = cnt[lb];
            if (lane < c) {
                int gp = bse[lb] + lane;
                if (gp < CAP) sorted_b[lb * CAP + gp] = buf[lb * STG + lane];
            }
        }
    } else {
        // ---- table role: 8 grid points per block, 2 at a time (128 thr each)
        float* red = (float*)bse;
        const int tblk = blockIdx.x - APPEND_BLOCKS;
        const int grp = threadIdx.x >> 7;       // 0 or 1
        const int k = threadIdx.x & 127;
        const int kk = k < 100 ? k : 99;
        for (int rep = 0; rep < 4; ++rep) {
            int point = tblk * 8 + rep * 2 + grp;
            float g = -1.0f + (float)point * (1.0f / (float)(TSIZE / 2));
            float acc = b2[kk];
            #pragma unroll 4
            for (int j = 0; j < 100; ++j) {
                float h1 = leaky(g * w1[j] + b1[j]);
                acc += h1 * w2[j * 100 + kk];
            }
            float part = (k < 100) ? leaky(acc) * w3[k] : 0.0f;
            #pragma unroll
            for (int off = 32; off > 0; off >>= 1)
                part += __shfl_down(part, off, 64);
            __syncthreads();
            if ((threadIdx.x & 63) == 0) red[threadIdx.x >> 6] = part;
            __syncthreads();
            if (k == 0 && point <= TSIZE)
                tab[point] = red[grp * 2] + red[grp * 2 + 1] + b3[0];
        }
    }
}

// ---------- per-block: 2 buckets, stab loaded once; voxels written once ----------
__global__ __launch_bounds__(256) void accum_kernel(
        const unsigned* __restrict__ sorted, const int* __restrict__ curs,
        const float* __restrict__ tab, float* __restrict__ out) {
    __shared__ float acc[2 * Cc * Ww];      // 4320 floats: [(dy*Ww+x)*Cc + i]
    __shared__ float stab[TSIZE + 1];

    for (int i = threadIdx.x; i <= TSIZE; i += 256) stab[i] = tab[i];

    for (int q = 0; q < 2; ++q) {
        const int bkt = blockIdx.x * 2 + q;     // (b*2+p)*TPB + ytile
        const int b2p = bkt / TPB;
        const int ytile = bkt % TPB;

        for (int i = threadIdx.x; i < 2 * Cc * Ww; i += 256) acc[i] = 0.0f;
        int cnt = curs[bkt];
        if (cnt > CAP) cnt = CAP;
        const unsigned* sb = sorted + (size_t)bkt * CAP;
        __syncthreads();

        for (int e = threadIdx.x; e < cnt; e += 256) {
            unsigned w = sb[e];
            int x = w & 255;
            int y = (w >> 8) & 255;
            int m = (int)(w >> 17);
            int lbase = ((y & 1) * Ww + x) * Cc;    // 9 consecutive floats
            float tfr = (float)m * (1.0f / 32768.0f);
            int U = m + 32768;                       // table coord, 1/32 units
            #pragma unroll
            for (int i = 0; i < Cc; ++i) {
                int Ui = U - i * 4096;               // exact: (i/8)*1024*32
                int iu = Ui >> 5;                    // 0..2047
                float fr = (float)(Ui & 31) * 0.03125f;
                float v0 = stab[iu];
                float v1 = stab[iu + 1];
                atomicAdd(&acc[lbase + i], tfr * (v0 + fr * (v1 - v0)));
            }
        }
        __syncthreads();

        const int y0 = ytile * 2;
        for (int j = threadIdx.x; j < 2 * Cc * Ww; j += 256) {
            int i = j / (2 * Ww);
            int r = j % (2 * Ww);
            int dy = r / Ww;
            int x = r % Ww;                          // coalesced stores
            __builtin_nontemporal_store(
                acc[(dy * Ww + x) * Cc + i],
                &out[(b2p * Cc + i) * WH + (y0 + dy) * Ww + x]);
        }
        __syncthreads();    // protect acc before next bucket's zeroing
    }
}

// ---------- fallback path (round-1 verified) ----------
__global__ __launch_bounds__(128) void build_table_kernel(
        const float* __restrict__ w1, const float* __restrict__ b1,
        const float* __restrict__ w2, const float* __restrict__ b2,
        const float* __restrict__ w3, const float* __restrict__ b3,
        float* __restrict__ tab) {
    const int i = blockIdx.x;
    const int k = threadIdx.x;
    const int kk = k < 100 ? k : 99;
    const float g = -1.0f + (2.0f / (float)TSIZE) * (float)i;
    float acc = b2[kk];
    #pragma unroll 4
    for (int j = 0; j < 100; ++j) {
        float h1 = leaky(g * w1[j] + b1[j]);
        acc += h1 * w2[j * 100 + kk];
    }
    float part = 0.0f;
    if (k < 100) part = leaky(acc) * w3[k];
    #pragma unroll
    for (int off = 32; off > 0; off >>= 1) part += __shfl_down(part, off, 64);
    __shared__ float red[2];
    if ((k & 63) == 0) red[k >> 6] = part;
    __syncthreads();
    if (k == 0) tab[i] = red[0] + red[1] + b3[0];
}

__global__ __launch_bounds__(256) void scatter_kernel(
        const float* __restrict__ t,
        const int* __restrict__ ex, const int* __restrict__ ey,
        const int* __restrict__ ep,
        const float* __restrict__ tab,
        float* __restrict__ out) {
    __shared__ float stab[TSIZE + 1];
    for (int i = threadIdx.x; i < TSIZE + 1; i += 256) stab[i] = tab[i];
    __syncthreads();
    const int b = blockIdx.x & 7;
    const int chunk = blockIdx.x >> 3;
    const int e = chunk * 256 + threadIdx.x;
    if (e >= Nn) return;
    const int gi = b * Nn + e;
    const float tf = t[gi];
    const int base = ex[gi] + Ww * ey[gi] + WHC * ep[gi] + 2 * WHC * b;
    #pragma unroll
    for (int i = 0; i < Cc; ++i) {
        float ts = tf - 0.125f * (float)i;
        float u = (ts + 1.0f) * (float)(TSIZE / 2);
        u = fmaxf(u, 0.0f);
        int iu = (int)u;
        if (iu > TSIZE - 1) iu = TSIZE - 1;
        float fr = u - (float)iu;
        float v0 = stab[iu];
        float v1 = stab[iu + 1];
        atomicAdd(out + base + WH * i, tf * (v0 + fr * (v1 - v0)));
    }
}

extern "C" void kernel_launch(void* const* d_in, const int* in_sizes, int n_in,
                              void* d_out, int out_size, void* d_ws, size_t ws_size,
                              hipStream_t stream) {
    // setup_inputs order: t, w1, b1, w2, b2, w3, b3, x, y, p
    const float* t  = (const float*)d_in[0];
    const float* w1 = (const float*)d_in[1];
    const float* b1 = (const float*)d_in[2];
    const float* w2 = (const float*)d_in[3];
    const float* b2 = (const float*)d_in[4];
    const float* w3 = (const float*)d_in[5];
    const float* b3 = (const float*)d_in[6];
    const int*   ex = (const int*)d_in[7];
    const int*   ey = (const int*)d_in[8];
    const int*   ep = (const int*)d_in[9];
    float* out = (float*)d_out;
    char* ws = (char*)d_ws;

    if (ws_size >= (size_t)WS_NEED) {
        unsigned* sorted = (unsigned*)(ws + SORT_OFF);
        float*    tab    = (float*)(ws + TAB_OFF);
        int*      curs   = (int*)(ws + CURS_OFF);

        hipMemsetAsync(curs, 0, NBKT * sizeof(int), stream);
        prep_kernel<<<PREP_BLOCKS, 256, 0, stream>>>(
            ex, ey, ep, t, w1, b1, w2, b2, w3, b3, curs, sorted, tab);
        accum_kernel<<<NBKT / 2, 256, 0, stream>>>(sorted, curs, tab, out);
    } else {
        // Fallback: direct global-atomic scatter.
        float* tab = (float*)ws;  // needs (TSIZE+1)*4 B
        hipMemsetAsync(d_out, 0, (size_t)out_size * sizeof(float), stream);
        build_table_kernel<<<TSIZE + 1, 128, 0, stream>>>(w1, b1, w2, b2, w3, b3, tab);
        const int chunks = (Nn + 255) / 256;
        scatter_kernel<<<chunks * Bb, 256, 0, stream>>>(t, ex, ey, ep, tab, out);
    }
}

// Round 5
// 123.597 us; speedup vs baseline: 1.3048x; 1.3048x over previous
//
#include <hip/hip_runtime.h>
#include <hip/hip_bf16.h>

// Problem constants (from reference)
#define Cc   9
#define Hh   180
#define Ww   240
#define Bb   8
#define Nn   100000
#define WH   (Ww * Hh)        // 43200
#define WHC  (WH * Cc)        // 388800

// value_layer lookup table: piecewise-linear in ts over [-1,1]. 2048 intervals.
#define TSIZE 2048

// Bucketing: bucket = (batch, polarity, 2-row y-tile). mean 556 ev/bucket.
#define TPB   90               // y-tiles per batch
#define LBKT  (2 * TPB)        // 180 local buckets per batch
#define NBKT  (LBKT * Bb)      // 1440
#define CAP   1024             // >> max bucket fill (~670); overflow guarded

#define CHUNK 2048
#define CHUNKS_PB 49                       // ceil(100000/2048)
#define APPEND_BLOCKS (CHUNKS_PB * Bb)     // 392
#define TABLE_BLOCKS  257                  // 8 table points per block
#define PREP_BLOCKS   (APPEND_BLOCKS + TABLE_BLOCKS)  // 649
#define STG   64                           // staging entries per bucket

// Workspace layout (bytes)
#define SORT_OFF 0                              // uint[NBKT*CAP] = 5,898,240
#define TAB_OFF  (NBKT * CAP * 4)               // float[2049]    = 8,196
#define CURS_OFF (TAB_OFF + (TSIZE + 1) * 4)    // int[1440]      = 5,760
#define WS_NEED  (CURS_OFF + NBKT * 4)          // 5,912,196

#define NCELL 480                               // 2 rows x 240 cols per bucket

__device__ __forceinline__ float leaky(float v) {
    return v >= 0.0f ? v : 0.1f * v;
}

// ---------- fused prep kernel (unchanged from R4) ----------
__global__ __launch_bounds__(256) void prep_kernel(
        const int* __restrict__ ex, const int* __restrict__ ey,
        const int* __restrict__ ep, const float* __restrict__ t,
        const float* __restrict__ w1, const float* __restrict__ b1,
        const float* __restrict__ w2, const float* __restrict__ b2,
        const float* __restrict__ w3, const float* __restrict__ b3,
        int* __restrict__ curs, unsigned* __restrict__ sorted,
        float* __restrict__ tab) {
    __shared__ unsigned buf[LBKT * STG];   // 46,080 B staging
    __shared__ int cnt[LBKT];
    __shared__ int bse[LBKT];

    if (blockIdx.x < APPEND_BLOCKS) {
        const int b = blockIdx.x / CHUNKS_PB;
        const int chunk = blockIdx.x % CHUNKS_PB;
        for (int i = threadIdx.x; i < LBKT; i += 256) cnt[i] = 0;
        __syncthreads();

        int* curs_b = curs + b * LBKT;
        unsigned* sorted_b = sorted + (size_t)b * LBKT * CAP;

        const int base_e = chunk * CHUNK + threadIdx.x;
        #pragma unroll
        for (int k = 0; k < 8; ++k) {
            int e = base_e + k * 256;
            if (e < Nn) {
                int gi = b * Nn + e;
                int x = __builtin_nontemporal_load(ex + gi);
                int y = __builtin_nontemporal_load(ey + gi);
                int p = __builtin_nontemporal_load(ep + gi);
                float tf = __builtin_nontemporal_load(t + gi);
                int m = (int)(tf * 32768.0f + 0.5f);
                if (m > 32767) m = 32767;
                unsigned wv = (unsigned)x | ((unsigned)y << 8) |
                              ((unsigned)p << 16) | ((unsigned)m << 17);
                int lb = p * TPB + (y >> 1);
                int pos = atomicAdd(&cnt[lb], 1);
                if (pos < STG) {
                    buf[lb * STG + pos] = wv;
                } else {
                    int gp = atomicAdd(&curs_b[lb], 1);
                    if (gp < CAP) sorted_b[lb * CAP + gp] = wv;
                }
            }
        }
        __syncthreads();
        if (threadIdx.x < LBKT) {
            int c = cnt[threadIdx.x];
            if (c > STG) c = STG;
            cnt[threadIdx.x] = c;
            bse[threadIdx.x] = c ? atomicAdd(&curs_b[threadIdx.x], c) : 0;
        }
        __syncthreads();
        const int wid = threadIdx.x >> 6;
        const int lane = threadIdx.x & 63;
        for (int lb = wid; lb < LBKT; lb += 4) {
            int c = cnt[lb];
            if (lane < c) {
                int gp = bse[lb] + lane;
                if (gp < CAP) sorted_b[lb * CAP + gp] = buf[lb * STG + lane];
            }
        }
    } else {
        float* red = (float*)bse;
        const int tblk = blockIdx.x - APPEND_BLOCKS;
        const int grp = threadIdx.x >> 7;       // 0 or 1
        const int k = threadIdx.x & 127;
        const int kk = k < 100 ? k : 99;
        for (int rep = 0; rep < 4; ++rep) {
            int point = tblk * 8 + rep * 2 + grp;
            float g = -1.0f + (float)point * (1.0f / (float)(TSIZE / 2));
            float acc = b2[kk];
            #pragma unroll 4
            for (int j = 0; j < 100; ++j) {
                float h1 = leaky(g * w1[j] + b1[j]);
                acc += h1 * w2[j * 100 + kk];
            }
            float part = (k < 100) ? leaky(acc) * w3[k] : 0.0f;
            #pragma unroll
            for (int off = 32; off > 0; off >>= 1)
                part += __shfl_down(part, off, 64);
            __syncthreads();
            if ((threadIdx.x & 63) == 0) red[threadIdx.x >> 6] = part;
            __syncthreads();
            if (k == 0 && point <= TSIZE)
                tab[point] = red[grp * 2] + red[grp * 2 + 1] + b3[0];
        }
    }
}

// ---------- accum: in-block counting sort by pixel-cell, register bins ----------
// No LDS atomics in the accumulation; each voxel written exactly once,
// coalesced per bin; empty cells store 0 (output zero-fill included).
__global__ __launch_bounds__(256) void accum_kernel(
        const unsigned* __restrict__ sorted, const int* __restrict__ curs,
        const float* __restrict__ tab, float* __restrict__ out) {
    __shared__ float2 stab2[TSIZE + 1];    // (v, dv): one b64 read per bin
    __shared__ unsigned evsorted[CAP];
    __shared__ int hist[512];              // 480 cells, padded to 512
    __shared__ int wsum[8];

    const int bkt = blockIdx.x;            // (b*2+p)*TPB + ytile
    const int b2p = bkt / TPB;
    const int ytile = bkt % TPB;
    const int tid = threadIdx.x;
    const int lane = tid & 63;
    const int wid = tid >> 6;

    for (int i = tid; i <= TSIZE; i += 256) {
        float v = tab[i];
        float v1 = (i < TSIZE) ? tab[i + 1] : v;
        stab2[i] = make_float2(v, v1 - v);
    }
    for (int i = tid; i < 512; i += 256) hist[i] = 0;

    int cnt = curs[bkt];
    if (cnt > CAP) cnt = CAP;
    const unsigned* sb = sorted + (size_t)bkt * CAP;
    __syncthreads();

    // Pass 1: load events to registers, count per cell (<=4 atomic rtns/thread)
    unsigned wreg[4];
    #pragma unroll
    for (int j = 0; j < 4; ++j) {
        int e = tid + j * 256;
        wreg[j] = 0;
        if (e < cnt) {
            unsigned w = sb[e];
            wreg[j] = w;
            int cell = ((w >> 8) & 1) * Ww + (w & 255);
            atomicAdd(&hist[cell], 1);
        }
    }
    __syncthreads();

    // Exclusive scan over 512 entries: per-wave shfl scans + serial seg merge
    int own[2], incl[2];
    #pragma unroll
    for (int r = 0; r < 2; ++r) {
        int i = r * 256 + tid;
        int x = hist[i];
        own[r] = x;
        #pragma unroll
        for (int d = 1; d < 64; d <<= 1) {
            int y = __shfl_up(x, d, 64);
            if (lane >= d) x += y;
        }
        incl[r] = x;
        if (lane == 63) wsum[r * 4 + wid] = x;
    }
    __syncthreads();
    if (tid == 0) {
        int a = 0;
        #pragma unroll
        for (int s = 0; s < 8; ++s) { int v = wsum[s]; wsum[s] = a; a += v; }
    }
    __syncthreads();
    #pragma unroll
    for (int r = 0; r < 2; ++r) {
        int i = r * 256 + tid;
        hist[i] = wsum[r * 4 + wid] + incl[r] - own[r];  // exclusive cursor
    }
    __syncthreads();

    // Pass 2: scatter into cell order (cursor bump; hist[c] -> end offset)
    #pragma unroll
    for (int j = 0; j < 4; ++j) {
        int e = tid + j * 256;
        if (e < cnt) {
            unsigned w = wreg[j];
            int cell = ((w >> 8) & 1) * Ww + (w & 255);
            int pos = atomicAdd(&hist[cell], 1);
            evsorted[pos] = w;
        }
    }
    __syncthreads();

    // Phase B: each thread owns cells tid, tid+256; bins in registers.
    const int y0 = ytile * 2;
    for (int c = tid; c < NCELL; c += 256) {
        int s = c ? hist[c - 1] : 0;
        int e_end = hist[c];
        float bin[Cc];
        #pragma unroll
        for (int i = 0; i < Cc; ++i) bin[i] = 0.0f;
        for (int e = s; e < e_end; ++e) {
            unsigned w = evsorted[e];
            int m = (int)(w >> 17);
            float tfr = (float)m * (1.0f / 32768.0f);
            int U = m + 32768;                   // table coord, 1/32 units
            #pragma unroll
            for (int i = 0; i < Cc; ++i) {
                int Ui = U - i * 4096;           // exact: (i/8)*1024*32
                int iu = Ui >> 5;                // 0..2047
                float fr = (float)(Ui & 31) * 0.03125f;
                float2 td = stab2[iu];
                bin[i] += tfr * (td.x + fr * td.y);
            }
        }
        int dy = c / Ww;
        int x = c % Ww;                          // consecutive tid -> coalesced
        #pragma unroll
        for (int i = 0; i < Cc; ++i)
            out[(b2p * Cc + i) * WH + (y0 + dy) * Ww + x] = bin[i];
    }
}

// ---------- fallback path (round-1 verified) ----------
__global__ __launch_bounds__(128) void build_table_kernel(
        const float* __restrict__ w1, const float* __restrict__ b1,
        const float* __restrict__ w2, const float* __restrict__ b2,
        const float* __restrict__ w3, const float* __restrict__ b3,
        float* __restrict__ tab) {
    const int i = blockIdx.x;
    const int k = threadIdx.x;
    const int kk = k < 100 ? k : 99;
    const float g = -1.0f + (2.0f / (float)TSIZE) * (float)i;
    float acc = b2[kk];
    #pragma unroll 4
    for (int j = 0; j < 100; ++j) {
        float h1 = leaky(g * w1[j] + b1[j]);
        acc += h1 * w2[j * 100 + kk];
    }
    float part = 0.0f;
    if (k < 100) part = leaky(acc) * w3[k];
    #pragma unroll
    for (int off = 32; off > 0; off >>= 1) part += __shfl_down(part, off, 64);
    __shared__ float red[2];
    if ((k & 63) == 0) red[k >> 6] = part;
    __syncthreads();
    if (k == 0) tab[i] = red[0] + red[1] + b3[0];
}

__global__ __launch_bounds__(256) void scatter_kernel(
        const float* __restrict__ t,
        const int* __restrict__ ex, const int* __restrict__ ey,
        const int* __restrict__ ep,
        const float* __restrict__ tab,
        float* __restrict__ out) {
    __shared__ float stab[TSIZE + 1];
    for (int i = threadIdx.x; i < TSIZE + 1; i += 256) stab[i] = tab[i];
    __syncthreads();
    const int b = blockIdx.x & 7;
    const int chunk = blockIdx.x >> 3;
    const int e = chunk * 256 + threadIdx.x;
    if (e >= Nn) return;
    const int gi = b * Nn + e;
    const float tf = t[gi];
    const int base = ex[gi] + Ww * ey[gi] + WHC * ep[gi] + 2 * WHC * b;
    #pragma unroll
    for (int i = 0; i < Cc; ++i) {
        float ts = tf - 0.125f * (float)i;
        float u = (ts + 1.0f) * (float)(TSIZE / 2);
        u = fmaxf(u, 0.0f);
        int iu = (int)u;
        if (iu > TSIZE - 1) iu = TSIZE - 1;
        float fr = u - (float)iu;
        float v0 = stab[iu];
        float v1 = stab[iu + 1];
        atomicAdd(out + base + WH * i, tf * (v0 + fr * (v1 - v0)));
    }
}

extern "C" void kernel_launch(void* const* d_in, const int* in_sizes, int n_in,
                              void* d_out, int out_size, void* d_ws, size_t ws_size,
                              hipStream_t stream) {
    // setup_inputs order: t, w1, b1, w2, b2, w3, b3, x, y, p
    const float* t  = (const float*)d_in[0];
    const float* w1 = (const float*)d_in[1];
    const float* b1 = (const float*)d_in[2];
    const float* w2 = (const float*)d_in[3];
    const float* b2 = (const float*)d_in[4];
    const float* w3 = (const float*)d_in[5];
    const float* b3 = (const float*)d_in[6];
    const int*   ex = (const int*)d_in[7];
    const int*   ey = (const int*)d_in[8];
    const int*   ep = (const int*)d_in[9];
    float* out = (float*)d_out;
    char* ws = (char*)d_ws;

    if (ws_size >= (size_t)WS_NEED) {
        unsigned* sorted = (unsigned*)(ws + SORT_OFF);
        float*    tab    = (float*)(ws + TAB_OFF);
        int*      curs   = (int*)(ws + CURS_OFF);

        hipMemsetAsync(curs, 0, NBKT * sizeof(int), stream);
        prep_kernel<<<PREP_BLOCKS, 256, 0, stream>>>(
            ex, ey, ep, t, w1, b1, w2, b2, w3, b3, curs, sorted, tab);
        accum_kernel<<<NBKT, 256, 0, stream>>>(sorted, curs, tab, out);
    } else {
        // Fallback: direct global-atomic scatter.
        float* tab = (float*)ws;  // needs (TSIZE+1)*4 B
        hipMemsetAsync(d_out, 0, (size_t)out_size * sizeof(float), stream);
        build_table_kernel<<<TSIZE + 1, 128, 0, stream>>>(w1, b1, w2, b2, w3, b3, tab);
        const int chunks = (Nn + 255) / 256;
        scatter_kernel<<<chunks * Bb, 256, 0, stream>>>(t, ex, ey, ep, tab, out);
    }
}